// Round 1
// baseline (1316.317 us; speedup 1.0000x reference)
//
#include <hip/hip_runtime.h>
#include <stdint.h>
#include <math.h>

// S2Convolution: BATCH=8, FIN=64, FOUT=128, B_IN=32, B_OUT=16, NL=16, MDIM=31,
// grid 4x8=32, out [8,128,32,32,32] fp32.
//
// Pipeline: consts (Wigner-d, fp64) -> xhat -> khc -> z(valid-packed fp32)
//           -> fmn(bf16) -> t(bf16) -> out(fp32).

#define PI_D 3.14159265358979323846
#define SCALING_F 0.002762135864009951f   // 1/sqrt(32*64*16^4/32^2)

// ws offsets in 4-byte words. T overlays KHC+Z (dead by the time k_t runs).
#define OFF_WANA 0            // 64*16*31            = 31744
#define OFF_FKR  31744        // 32*16*31            = 15872
#define OFF_FKI  47616        // 15872
#define OFF_DP   63488        // 32*5456             = 174592
#define OFF_XHAT 238080       // 16*31*8*64*2        = 507904
#define OFF_T    745984       // 8*128*32*31*32      = 32505856 (bf16-pair words)
#define OFF_KHC  745984       // 16*31*128*64*2      = 8126464  (overlay inside T)
#define OFF_Z    8872448      // 1024*5456*2         = 11173888 (overlay inside T)
#define OFF_FMN  33251840     // 8*128*32*961        = 31490048 (bf16-pair words)
// total = 64741888 words = 259 MB

__device__ __constant__ int c_offs[17] = {0,1,10,35,84,165,286,455,680,969,1330,1771,2300,2925,3654,4495,5456};

__device__ inline double ipow_d(double x, int e){
  double r = 1.0;
  while (e > 0){ if (e & 1) r *= x; x *= x; e >>= 1; }
  return r;
}

// Wigner small-d d^l_{m1,m2}(beta), fp64, matches reference _wigner_d
__device__ double wig_d(int l, int m1, int m2, double beta, const double* LF){
  double c = cos(0.5*beta), s = sin(0.5*beta);
  double sum = 0.0;
  for (int k = 0; k <= 2*l; ++k){
    int a1 = l + m2 - k, a3 = m1 - m2 + k, a4 = l - m1 - k;
    if (a1 < 0 || a3 < 0 || a4 < 0) continue;
    double logc = 0.5*(LF[l+m1]+LF[l-m1]+LF[l+m2]+LF[l-m2]) - LF[a1] - LF[k] - LF[a3] - LF[a4];
    double t = exp(logc) * ipow_d(c, a1 + a4) * ipow_d(s, a3 + k);
    sum += (a3 & 1) ? -t : t;  // (-1)^(m1-m2+k)
  }
  return sum;
}

__device__ inline uint32_t f2bf(float f){
  uint32_t u = __float_as_uint(f);
  return (u + 0x7fffu + ((u >> 16) & 1u)) >> 16;   // RNE
}
__device__ inline float bf2f(uint32_t h){ return __uint_as_float((h & 0xffffu) << 16); }
__device__ inline uint32_t pack2(float a, float b){ return f2bf(a) | (f2bf(b) << 16); }

#define LF_INIT \
  __shared__ double LF[40]; \
  if (threadIdx.x == 0){ LF[0] = 0.0; double acc_ = 0.0; for (int n_ = 1; n_ < 40; ++n_){ acc_ += log((double)n_); LF[n_] = acc_; } } \
  __syncthreads();

// W_ANA[j][l][m] = w_j * d^l_{m',0}(beta_in_j), |m'|<=l else 0
__global__ void k_wana(float* __restrict__ ws){
  LF_INIT
  int id = blockIdx.x*256 + threadIdx.x;
  if (id >= 31744) return;
  int m = id % 31, l = (id / 31) & 15, j = id / 496;
  int mp = m - 15, amp = mp < 0 ? -mp : mp;
  float val = 0.f;
  if (amp <= l){
    double beta = PI_D*(2*j + 0.5)/128.0;
    double wsum = 0.0;
    for (int kk = 0; kk < 32; ++kk) wsum += sin(beta*(2*kk+1))/(double)(2*kk+1);
    double w = (2.0*PI_D/64.0)*(2.0/32.0)*sin(beta)*wsum;
    val = (float)(w * wig_d(l, mp, 0, beta, LF));
  }
  ws[OFF_WANA + id] = val;
}

// FK[g][l][n] = d^l_{n',0}(beta_g) * e^{i n' alpha_g}
__global__ void k_fk(float* __restrict__ ws){
  LF_INIT
  int id = blockIdx.x*256 + threadIdx.x;
  if (id >= 15872) return;
  int n = id % 31, l = (id / 31) & 15, g = id / 496;
  int np = n - 15, anp = np < 0 ? -np : np;
  float vr = 0.f, vi = 0.f;
  if (anp <= l){
    double beta = PI_D*((double)((g >> 3) + 1))/32.0;
    double alpha = (PI_D/4.0)*(double)(g & 7);
    double d = wig_d(l, np, 0, beta, LF);
    vr = (float)(d*cos(np*alpha));
    vi = (float)(d*sin(np*alpha));
  }
  ws[OFF_FKR + id] = vr;
  ws[OFF_FKI + id] = vi;
}

// Dp[k][packed(l,im,in)] = (2l+1)*d^l_{im-l,in-l}(beta_out_k)
__global__ void k_dsyn(float* __restrict__ ws){
  LF_INIT
  int k = blockIdx.x >> 4, l = blockIdx.x & 15;
  int n21 = 2*l + 1, items = n21*n21;
  double beta = PI_D*(2*k + 0.5)/64.0;
  float fl = (float)(2*l + 1);
  for (int item = threadIdx.x; item < items; item += 256){
    int im = item / n21, in = item - (item/n21)*n21;
    ws[OFF_DP + k*5456 + c_offs[l] + item] = fl * (float)wig_d(l, im - l, in - l, beta, LF);
  }
}

// xhat[l][m][b][i] (cpx) = sum_j W_ANA[j,l,m] * (sum_a x[b,i,j,a] e^{-i m' 2pi a/64})
__global__ void k_xhat(const float* __restrict__ x, float* __restrict__ ws){
  __shared__ float xl[4096];
  __shared__ float c64[64], s64[64];
  __shared__ float xmr[1984], xmi[1984];
  int tid = threadIdx.x;
  int b = blockIdx.x >> 6, i = blockIdx.x & 63;
  const float* xp = x + (b*64 + i)*4096;
  for (int idx = tid; idx < 4096; idx += 256) xl[idx] = xp[idx];
  if (tid < 64){ double a = 2.0*PI_D*tid/64.0; c64[tid] = (float)cos(a); s64[tid] = (float)sin(a); }
  __syncthreads();
  for (int item = tid; item < 1984; item += 256){
    int j = item / 31, m = item - (item/31)*31, mp = m - 15;
    float re = 0.f, im = 0.f;
    const float* xr = xl + j*64;
    for (int a = 0; a < 64; ++a){
      int p = (mp*a) & 63;
      re += xr[a]*c64[p];
      im -= xr[a]*s64[p];
    }
    xmr[item] = re; xmi[item] = im;
  }
  __syncthreads();
  for (int item = tid; item < 496; item += 256){
    int l = item / 31, m = item - (item/31)*31, mp = m - 15;
    int amp = mp < 0 ? -mp : mp;
    float rr = 0.f, ri = 0.f;
    if (amp <= l){
      for (int j = 0; j < 64; ++j){
        float w = ws[OFF_WANA + j*496 + item];
        rr += w * xmr[j*31 + m];
        ri += w * xmi[j*31 + m];
      }
    }
    int dst = OFF_XHAT + (item*8 + b)*128 + i*2;
    ws[dst] = rr; ws[dst+1] = ri;
  }
}

// khc[l][n][o][i] = SCALING * sum_g kernel[i,o,g] * conj(FK[g,l,n])
__global__ void k_khc(const float* __restrict__ kern, float* __restrict__ ws){
  __shared__ float kl[64*33];
  __shared__ float fr[992], fi[992];
  int tid = threadIdx.x;
  int o = blockIdx.x >> 4, l = blockIdx.x & 15;
  for (int idx = tid; idx < 2048; idx += 256){
    int i = idx >> 5, g = idx & 31;
    kl[i*33 + g] = kern[(i*128 + o)*32 + g];
  }
  for (int idx = tid; idx < 992; idx += 256){
    int g = idx / 31, n = idx - (idx/31)*31;
    fr[idx] = ws[OFF_FKR + g*496 + l*31 + n];
    fi[idx] = ws[OFF_FKI + g*496 + l*31 + n];
  }
  __syncthreads();
  for (int item = tid; item < 1984; item += 256){
    int n = item >> 6, i = item & 63;
    float ar = 0.f, ai = 0.f;
    for (int g = 0; g < 32; ++g){
      float kv = kl[i*33 + g];
      ar += kv * fr[g*31 + n];
      ai -= kv * fi[g*31 + n];
    }
    int dst = OFF_KHC + ((l*31 + n)*128 + o)*128 + i*2;
    ws[dst] = SCALING_F * ar;
    ws[dst+1] = SCALING_F * ai;
  }
}

// z[b][o][packed(l,im,in)] = sum_i xhat[l,m,b,i]*khc[l,n,o,i]  (khc already conj)
__global__ void k_z(float* __restrict__ ws){
  __shared__ float xs[31*134];
  __shared__ float ks[31*134];
  int tid = threadIdx.x;
  int bo = blockIdx.x;
  int b = bo >> 7, o = bo & 127;
  for (int l = 0; l < 16; ++l){
    int n21 = 2*l + 1, mbase = 15 - l, nw = n21*128, l2 = 2*l;
    for (int idx = tid; idx < nw; idx += 256){
      int r = idx >> 7, w = idx & 127;
      xs[r*134 + w] = ws[OFF_XHAT + ((l*31 + mbase + r)*8 + b)*128 + w];
      ks[r*134 + w] = ws[OFF_KHC + ((l*31 + mbase + r)*128 + o)*128 + w];
    }
    __syncthreads();
    int tdim = l + 1;
    int zb = OFF_Z + (bo*5456 + c_offs[l])*2;
    for (int t = tid; t < tdim*tdim; t += 256){
      int tm = t / tdim, tn = t - (t/tdim)*tdim;
      int im0 = 2*tm, in0 = 2*tn;
      int im1 = im0 + 1; if (im1 > l2) im1 = l2;
      int in1 = in0 + 1; if (in1 > l2) in1 = l2;
      float z00r=0,z00i=0,z01r=0,z01i=0,z10r=0,z10i=0,z11r=0,z11i=0;
      const float* x0 = xs + im0*134;
      const float* x1 = xs + im1*134;
      const float* k0 = ks + in0*134;
      const float* k1 = ks + in1*134;
      for (int i = 0; i < 64; ++i){
        float x0r = x0[2*i], x0i = x0[2*i+1];
        float x1r = x1[2*i], x1i = x1[2*i+1];
        float k0r = k0[2*i], k0i = k0[2*i+1];
        float k1r = k1[2*i], k1i = k1[2*i+1];
        z00r += x0r*k0r - x0i*k0i; z00i += x0r*k0i + x0i*k0r;
        z01r += x0r*k1r - x0i*k1i; z01i += x0r*k1i + x0i*k1r;
        z10r += x1r*k0r - x1i*k0i; z10i += x1r*k0i + x1i*k0r;
        z11r += x1r*k1r - x1i*k1i; z11i += x1r*k1i + x1i*k1r;
      }
      int p00 = (im0*n21 + in0)*2, p01 = (im0*n21 + in1)*2;
      int p10 = (im1*n21 + in0)*2, p11 = (im1*n21 + in1)*2;
      ws[zb+p00] = z00r; ws[zb+p00+1] = z00i;
      ws[zb+p01] = z01r; ws[zb+p01+1] = z01i;
      ws[zb+p10] = z10r; ws[zb+p10+1] = z10i;
      ws[zb+p11] = z11r; ws[zb+p11+1] = z11i;
    }
    __syncthreads();
  }
}

// fmn[b,o,k,m,n] (bf16 pair) = sum_l Dp[k][pidx] * z[b,o][pidx]
__global__ void k_fmn(float* __restrict__ ws){
  __shared__ float zl[10912];
  int tid = threadIdx.x, bo = blockIdx.x;
  const float* zg = ws + OFF_Z + bo*10912;
  for (int idx = tid; idx < 10912; idx += 256) zl[idx] = zg[idx];
  __syncthreads();
  const float* Dp = ws + OFF_DP;
  uint32_t* fmn = reinterpret_cast<uint32_t*>(ws) + OFF_FMN + bo*32*961;
  for (int k = 0; k < 32; ++k){
    const float* Dk = Dp + k*5456;
    for (int item = tid; item < 961; item += 256){
      int m = item / 31, n = item - (item/31)*31;
      int mp = m - 15, np = n - 15;
      int am = mp < 0 ? -mp : mp, an = np < 0 ? -np : np;
      int lmin = am > an ? am : an;
      float Fr = 0.f, Fi = 0.f;
      for (int l = lmin; l < 16; ++l){
        int idx2 = c_offs[l] + (mp + l)*(2*l + 1) + (np + l);
        float d = Dk[idx2];
        Fr += d * zl[2*idx2];
        Fi += d * zl[2*idx2 + 1];
      }
      fmn[k*961 + item] = pack2(Fr, Fi);
    }
  }
}

// t[row=(bok,m)][c] = sum_n fmn[m,n] * e^{i 2pi c n'/32}
__global__ void k_t(float* __restrict__ ws){
  __shared__ float twc[32], tws[32];
  int tid = threadIdx.x;
  if (tid < 32){ double a = 2.0*PI_D*tid/32.0; twc[tid] = (float)cos(a); tws[tid] = (float)sin(a); }
  __syncthreads();
  int row = blockIdx.x*8 + (tid >> 5);
  int c = tid & 31;
  int bok = row / 31, m = row - bok*31;
  const uint32_t* fmn = reinterpret_cast<const uint32_t*>(ws) + OFF_FMN + bok*961 + m*31;
  float tr = 0.f, ti = 0.f;
  int p = (c*(-15)) & 31;   // start at n'=-15, increment by c each step (mod 32)
  #pragma unroll
  for (int n = 0; n < 31; ++n){
    uint32_t wv = fmn[n];
    float Fr = bf2f(wv), Fi = bf2f(wv >> 16);
    float C = twc[p], S = tws[p];
    tr += Fr*C - Fi*S;
    ti += Fr*S + Fi*C;
    p = (p + c) & 31;
  }
  reinterpret_cast<uint32_t*>(ws)[OFF_T + row*32 + c] = pack2(tr, ti);
}

// out[bok][a][c] = sum_m Re( t[m,c] * e^{i 2pi a m'/32} ) + bias[o]
__global__ void k_out(const float* __restrict__ bias, float* __restrict__ out,
                      const float* __restrict__ ws){
  __shared__ float twc[32], tws[32];
  int tid = threadIdx.x;
  if (tid < 32){ double a = 2.0*PI_D*tid/32.0; twc[tid] = (float)cos(a); tws[tid] = (float)sin(a); }
  __syncthreads();
  int bok = blockIdx.x;
  float bia = bias[(bok >> 5) & 127];
  const uint32_t* tt = reinterpret_cast<const uint32_t*>(ws) + OFF_T + bok*992;
  float* op = out + bok*1024;
  int c = tid & 31;
  int a0 = tid >> 5;                 // 4 a's per thread: a0, a0+8, a0+16, a0+24 share c
  float acc0 = 0.f, acc1 = 0.f, acc2 = 0.f, acc3 = 0.f;
  #pragma unroll
  for (int m = 0; m < 31; ++m){
    uint32_t wv = tt[m*32 + c];
    float trv = bf2f(wv), tiv = bf2f(wv >> 16);
    int mp = m - 15;
    int p0 = (a0*mp) & 31;
    int p1 = ((a0 + 8)*mp) & 31;
    int p2 = ((a0 + 16)*mp) & 31;
    int p3 = ((a0 + 24)*mp) & 31;
    acc0 += trv*twc[p0] - tiv*tws[p0];
    acc1 += trv*twc[p1] - tiv*tws[p1];
    acc2 += trv*twc[p2] - tiv*tws[p2];
    acc3 += trv*twc[p3] - tiv*tws[p3];
  }
  op[a0*32 + c]        = acc0 + bia;
  op[(a0+8)*32 + c]    = acc1 + bia;
  op[(a0+16)*32 + c]   = acc2 + bia;
  op[(a0+24)*32 + c]   = acc3 + bia;
}

extern "C" void kernel_launch(void* const* d_in, const int* in_sizes, int n_in,
                              void* d_out, int out_size, void* d_ws, size_t ws_size,
                              hipStream_t stream) {
  const float* x    = (const float*)d_in[0];   // [8,64,64,64]
  const float* kern = (const float*)d_in[1];   // [64,128,32]
  const float* bias = (const float*)d_in[2];   // [128]
  float* out = (float*)d_out;                  // [8,128,32,32,32]
  float* ws  = (float*)d_ws;

  k_wana<<<dim3(124),   dim3(256), 0, stream>>>(ws);
  k_fk  <<<dim3(62),    dim3(256), 0, stream>>>(ws);
  k_dsyn<<<dim3(512),   dim3(256), 0, stream>>>(ws);
  k_xhat<<<dim3(512),   dim3(256), 0, stream>>>(x, ws);
  k_khc <<<dim3(2048),  dim3(256), 0, stream>>>(kern, ws);
  k_z   <<<dim3(1024),  dim3(256), 0, stream>>>(ws);
  k_fmn <<<dim3(1024),  dim3(256), 0, stream>>>(ws);
  k_t   <<<dim3(126976),dim3(256), 0, stream>>>(ws);
  k_out <<<dim3(32768), dim3(256), 0, stream>>>(bias, out, ws);
}

// Round 2
// 640.108 us; speedup vs baseline: 2.0564x; 2.0564x over previous
//
#include <hip/hip_runtime.h>
#include <stdint.h>
#include <math.h>

// S2Convolution: BATCH=8, FIN=64, FOUT=128, B_IN=32, B_OUT=16, NL=16, MDIM=31,
// grid 4x8=32, out [8,128,32,32,32] fp32.
//
// v2: exploit conj symmetry (real inputs): fmn[-m,-n] = conj(fmn[m,n]) =>
// t[-m',c] = conj(t[m',c]) => only m' >= 0 computed anywhere downstream of xhat.
// k_fmn: Dk staged in LDS per k, uniform-l downward loop (conflict-free).
// k_t / k_out: radix-4 class accumulation (4 outputs per inner-loop pass).

#define PI_D 3.14159265358979323846
#define SCALING_F 0.002762135864009951f   // 1/sqrt(32*64*16^4/32^2)

// ws offsets in 4-byte words.
#define OFF_WANA 0            // 64*16*31            = 31744
#define OFF_FKR  31744        // 32*16*31            = 15872
#define OFF_FKI  47616        // 15872
#define OFF_DP2  63488        // 32*2856             = 91392
#define OFF_XHAT 154880       // 16*31*8*64*2        = 507904
#define OFF_KHC  662784       // 16*31*128*64*2      = 8126464
#define OFF_Z    8789248      // 1024*2856*2         = 5849088
#define OFF_FMN  14638336     // 1024*32*496         = 16252928 (bf16-pair words)
#define OFF_T    30891264     // 32768*16*32         = 16777216 (bf16-pair words)
// total = 47668480 words = 190.7 MB

// packed (l, m'>=0, n) offsets: c2_offs[l] = sum_{j<l} (j+1)(2j+1)
__device__ __constant__ int c2_offs[17] =
  {0,1,7,22,50,95,161,252,372,525,715,946,1222,1547,1925,2360,2856};

__device__ inline double ipow_d(double x, int e){
  double r = 1.0;
  while (e > 0){ if (e & 1) r *= x; x *= x; e >>= 1; }
  return r;
}

// Wigner small-d d^l_{m1,m2}(beta), fp64, matches reference _wigner_d
__device__ double wig_d(int l, int m1, int m2, double beta, const double* LF){
  double c = cos(0.5*beta), s = sin(0.5*beta);
  double sum = 0.0;
  for (int k = 0; k <= 2*l; ++k){
    int a1 = l + m2 - k, a3 = m1 - m2 + k, a4 = l - m1 - k;
    if (a1 < 0 || a3 < 0 || a4 < 0) continue;
    double logc = 0.5*(LF[l+m1]+LF[l-m1]+LF[l+m2]+LF[l-m2]) - LF[a1] - LF[k] - LF[a3] - LF[a4];
    double t = exp(logc) * ipow_d(c, a1 + a4) * ipow_d(s, a3 + k);
    sum += (a3 & 1) ? -t : t;  // (-1)^(m1-m2+k)
  }
  return sum;
}

__device__ inline uint32_t f2bf(float f){
  uint32_t u = __float_as_uint(f);
  return (u + 0x7fffu + ((u >> 16) & 1u)) >> 16;   // RNE
}
__device__ inline float bf2f(uint32_t h){ return __uint_as_float((h & 0xffffu) << 16); }
__device__ inline uint32_t pack2(float a, float b){ return f2bf(a) | (f2bf(b) << 16); }

#define LF_INIT \
  __shared__ double LF[40]; \
  if (threadIdx.x == 0){ LF[0] = 0.0; double acc_ = 0.0; for (int n_ = 1; n_ < 40; ++n_){ acc_ += log((double)n_); LF[n_] = acc_; } } \
  __syncthreads();

// W_ANA[j][l][m] = w_j * d^l_{m',0}(beta_in_j), |m'|<=l else 0  (full m kept)
__global__ void k_wana(float* __restrict__ ws){
  LF_INIT
  int id = blockIdx.x*256 + threadIdx.x;
  if (id >= 31744) return;
  int m = id % 31, l = (id / 31) & 15, j = id / 496;
  int mp = m - 15, amp = mp < 0 ? -mp : mp;
  float val = 0.f;
  if (amp <= l){
    double beta = PI_D*(2*j + 0.5)/128.0;
    double wsum = 0.0;
    for (int kk = 0; kk < 32; ++kk) wsum += sin(beta*(2*kk+1))/(double)(2*kk+1);
    double w = (2.0*PI_D/64.0)*(2.0/32.0)*sin(beta)*wsum;
    val = (float)(w * wig_d(l, mp, 0, beta, LF));
  }
  ws[OFF_WANA + id] = val;
}

// FK[g][l][n] = d^l_{n',0}(beta_g) * e^{i n' alpha_g}
__global__ void k_fk(float* __restrict__ ws){
  LF_INIT
  int id = blockIdx.x*256 + threadIdx.x;
  if (id >= 15872) return;
  int n = id % 31, l = (id / 31) & 15, g = id / 496;
  int np = n - 15, anp = np < 0 ? -np : np;
  float vr = 0.f, vi = 0.f;
  if (anp <= l){
    double beta = PI_D*((double)((g >> 3) + 1))/32.0;
    double alpha = (PI_D/4.0)*(double)(g & 7);
    double d = wig_d(l, np, 0, beta, LF);
    vr = (float)(d*cos(np*alpha));
    vi = (float)(d*sin(np*alpha));
  }
  ws[OFF_FKR + id] = vr;
  ws[OFF_FKI + id] = vi;
}

// Dp2[k][c2_offs[l] + m'*(2l+1) + (n'+l)] = (2l+1)*d^l_{m',n'}(beta_out_k), m'>=0
__global__ void k_dsyn(float* __restrict__ ws){
  LF_INIT
  int k = blockIdx.x >> 4, l = blockIdx.x & 15;
  int n21 = 2*l + 1, items = (l+1)*n21;
  double beta = PI_D*(2*k + 0.5)/64.0;
  float fl = (float)(2*l + 1);
  for (int item = threadIdx.x; item < items; item += 256){
    int im = item / n21, in = item - (item/n21)*n21;
    ws[OFF_DP2 + k*2856 + c2_offs[l] + item] = fl * (float)wig_d(l, im, in - l, beta, LF);
  }
}

// xhat[l][m=15+m'][b][i] (cpx), only m'>=0 rows
__global__ void k_xhat(const float* __restrict__ x, float* __restrict__ ws){
  __shared__ float xl[4096];
  __shared__ float c64[64], s64[64];
  __shared__ float xmr[1024], xmi[1024];
  int tid = threadIdx.x;
  int b = blockIdx.x >> 6, i = blockIdx.x & 63;
  const float* xp = x + (b*64 + i)*4096;
  for (int idx = tid; idx < 4096; idx += 256) xl[idx] = xp[idx];
  if (tid < 64){ double a = 2.0*PI_D*tid/64.0; c64[tid] = (float)cos(a); s64[tid] = (float)sin(a); }
  __syncthreads();
  for (int item = tid; item < 1024; item += 256){
    int j = item >> 4, mi = item & 15;      // m' = mi
    float re = 0.f, im = 0.f;
    const float* xr = xl + j*64;
    for (int a = 0; a < 64; ++a){
      int p = (mi*a) & 63;
      re += xr[a]*c64[p];
      im -= xr[a]*s64[p];
    }
    xmr[item] = re; xmi[item] = im;
  }
  __syncthreads();
  if (tid < 256){
    int l = tid >> 4, mi = tid & 15;
    if (mi <= l){
      float rr = 0.f, ri = 0.f;
      for (int j = 0; j < 64; ++j){
        float w = ws[OFF_WANA + j*496 + l*31 + 15 + mi];
        rr += w * xmr[j*16 + mi];
        ri += w * xmi[j*16 + mi];
      }
      int dst = OFF_XHAT + ((l*31 + 15 + mi)*8 + b)*128 + i*2;
      ws[dst] = rr; ws[dst+1] = ri;
    }
  }
}

// khc[l][n][o][i] = SCALING * sum_g kernel[i,o,g] * conj(FK[g,l,n])   (all n)
__global__ void k_khc(const float* __restrict__ kern, float* __restrict__ ws){
  __shared__ float kl[64*33];
  __shared__ float fr[992], fi[992];
  int tid = threadIdx.x;
  int o = blockIdx.x >> 4, l = blockIdx.x & 15;
  for (int idx = tid; idx < 2048; idx += 256){
    int i = idx >> 5, g = idx & 31;
    kl[i*33 + g] = kern[(i*128 + o)*32 + g];
  }
  for (int idx = tid; idx < 992; idx += 256){
    int g = idx / 31, n = idx - (idx/31)*31;
    fr[idx] = ws[OFF_FKR + g*496 + l*31 + n];
    fi[idx] = ws[OFF_FKI + g*496 + l*31 + n];
  }
  __syncthreads();
  for (int item = tid; item < 1984; item += 256){
    int n = item >> 6, i = item & 63;
    float ar = 0.f, ai = 0.f;
    for (int g = 0; g < 32; ++g){
      float kv = kl[i*33 + g];
      ar += kv * fr[g*31 + n];
      ai -= kv * fi[g*31 + n];
    }
    int dst = OFF_KHC + ((l*31 + n)*128 + o)*128 + i*2;
    ws[dst] = SCALING_F * ar;
    ws[dst+1] = SCALING_F * ai;
  }
}

// z[bo][c2-packed(l, m'>=0, n)] = sum_i xhat*khc (khc already conj)
__global__ void k_z(float* __restrict__ ws){
  __shared__ float xs[16*134];
  __shared__ float ks[31*134];
  int tid = threadIdx.x;
  int bo = blockIdx.x;
  int b = bo >> 7, o = bo & 127;
  for (int l = 0; l < 16; ++l){
    int n21 = 2*l + 1, mrows = l + 1, l2 = 2*l;
    int totalw = (mrows + n21)*128;
    for (int idx = tid; idx < totalw; idx += 256){
      int r = idx >> 7, w = idx & 127;
      if (r < mrows)
        xs[r*134 + w] = ws[OFF_XHAT + ((l*31 + 15 + r)*8 + b)*128 + w];
      else {
        int rr = r - mrows;
        ks[rr*134 + w] = ws[OFF_KHC + ((l*31 + (15 - l) + rr)*128 + o)*128 + w];
      }
    }
    __syncthreads();
    int tdm = (l + 2) >> 1, tdn = l + 1;
    int nt = tdm*tdn;
    int zb = OFF_Z + (bo*2856 + c2_offs[l])*2;
    for (int t = tid; t < nt; t += 256){
      int tm = t / tdn, tn = t - (t/tdn)*tdn;
      int im0 = 2*tm, in0 = 2*tn;
      int im1 = im0 + 1; if (im1 > l) im1 = l;
      int in1 = in0 + 1; if (in1 > l2) in1 = l2;
      float z00r=0,z00i=0,z01r=0,z01i=0,z10r=0,z10i=0,z11r=0,z11i=0;
      const float* x0 = xs + im0*134;
      const float* x1 = xs + im1*134;
      const float* k0 = ks + in0*134;
      const float* k1 = ks + in1*134;
      for (int i = 0; i < 64; ++i){
        float x0r = x0[2*i], x0i = x0[2*i+1];
        float x1r = x1[2*i], x1i = x1[2*i+1];
        float k0r = k0[2*i], k0i = k0[2*i+1];
        float k1r = k1[2*i], k1i = k1[2*i+1];
        z00r += x0r*k0r - x0i*k0i; z00i += x0r*k0i + x0i*k0r;
        z01r += x0r*k1r - x0i*k1i; z01i += x0r*k1i + x0i*k1r;
        z10r += x1r*k0r - x1i*k0i; z10i += x1r*k0i + x1i*k0r;
        z11r += x1r*k1r - x1i*k1i; z11i += x1r*k1i + x1i*k1r;
      }
      int p00 = (im0*n21 + in0)*2, p01 = (im0*n21 + in1)*2;
      int p10 = (im1*n21 + in0)*2, p11 = (im1*n21 + in1)*2;
      ws[zb+p00] = z00r; ws[zb+p00+1] = z00i;
      ws[zb+p01] = z01r; ws[zb+p01+1] = z01i;
      ws[zb+p10] = z10r; ws[zb+p10+1] = z10i;
      ws[zb+p11] = z11r; ws[zb+p11+1] = z11i;
    }
    __syncthreads();
  }
}

// fmn[bo,k,m'(0..15),n] (bf16 pair) = sum_l Dk * z ; Dk staged in LDS per k
__global__ void k_fmn(float* __restrict__ ws){
  __shared__ float zl[5712];
  __shared__ float dk[2856];
  int tid = threadIdx.x, bo = blockIdx.x;
  const float* zg = ws + OFF_Z + bo*5712;
  for (int idx = tid; idx < 5712; idx += 256) zl[idx] = zg[idx];
  uint32_t* fmn = reinterpret_cast<uint32_t*>(ws) + OFF_FMN + bo*32*496;
  for (int k = 0; k < 32; ++k){
    const float* Dg = ws + OFF_DP2 + k*2856;
    for (int idx = tid; idx < 2856; idx += 256) dk[idx] = Dg[idx];
    __syncthreads();
    for (int item = tid; item < 496; item += 256){
      int m = item / 31, n = item - (item/31)*31;
      int np = n - 15, an = np < 0 ? -np : np;
      int lmin = m > an ? m : an;
      float Fr = 0.f, Fi = 0.f;
      // downward loop: l is wave-uniform each iteration -> conflict-free LDS
      for (int l = 15; l >= lmin; --l){
        int idx2 = c2_offs[l] + m*(2*l + 1) + (n - 15 + l);
        float d = dk[idx2];
        float2 zv = *reinterpret_cast<const float2*>(zl + 2*idx2);
        Fr += d*zv.x; Fi += d*zv.y;
      }
      fmn[k*496 + item] = pack2(Fr, Fi);
    }
    __syncthreads();
  }
}

// t[bok, m'(0..15), c] = sum_n fmn[m',n] e^{i 2pi c n'/32}; radix-4 over c offsets
__global__ void k_t(float* __restrict__ ws){
  __shared__ float fl[992];
  __shared__ float twc[32], tws[32];
  int tid = threadIdx.x;
  const uint32_t* fg = reinterpret_cast<const uint32_t*>(ws) + OFF_FMN + (size_t)blockIdx.x*992;
  for (int idx = tid; idx < 992; idx += 256) reinterpret_cast<uint32_t*>(fl)[idx] = fg[idx];
  if (tid < 32){ double a = 2.0*PI_D*tid/32.0; twc[tid] = (float)cos(a); tws[tid] = (float)sin(a); }
  __syncthreads();
  int sub = tid >> 7, r = tid & 127;
  int m = r >> 3, cq = r & 7;
  const uint32_t* fr = reinterpret_cast<const uint32_t*>(fl) + sub*496 + m*31;
  float U0=0,U1=0,U2=0,U3=0,V0=0,V1=0,V2=0,V3=0;
  int p = (17*cq) & 31;   // (-15*cq) mod 32
  #pragma unroll
  for (int n = 0; n < 31; ++n){
    uint32_t wv = fr[n];
    float Fr = bf2f(wv), Fi = bf2f(wv >> 16);
    float C = twc[p], S = tws[p];
    float u = Fr*C - Fi*S;
    float v = Fr*S + Fi*C;
    int j = (n + 1) & 3;  // n' mod 4
    if      (j == 0){ U0 += u; V0 += v; }
    else if (j == 1){ U1 += u; V1 += v; }
    else if (j == 2){ U2 += u; V2 += v; }
    else            { U3 += u; V3 += v; }
    p = (p + cq) & 31;
  }
  int bok = blockIdx.x*2 + sub;
  uint32_t* tp = reinterpret_cast<uint32_t*>(ws) + OFF_T + (bok*16 + m)*32 + cq;
  tp[0]  = pack2(U0+U1+U2+U3, V0+V1+V2+V3);
  tp[8]  = pack2(U0-V1-U2+V3, V0+U1-V2-U3);
  tp[16] = pack2(U0-U1+U2-U3, V0-V1+V2-V3);
  tp[24] = pack2(U0+V1-U2-V3, V0-U1-V2+U3);
}

// out[bok][a][c] = t0.re + sum_{m'=1..15} 2 Re(t[m',c] e^{i 2pi a m'/32}) + bias
__global__ void k_out(const float* __restrict__ bias, float* __restrict__ out,
                      const float* __restrict__ ws){
  __shared__ float tl[512];
  __shared__ float twc[32], tws[32];
  int tid = threadIdx.x, bok = blockIdx.x;
  const uint32_t* tg = reinterpret_cast<const uint32_t*>(ws) + OFF_T + (size_t)bok*512;
  reinterpret_cast<uint32_t*>(tl)[tid]       = tg[tid];
  reinterpret_cast<uint32_t*>(tl)[tid + 256] = tg[tid + 256];
  if (tid < 32){ double a = 2.0*PI_D*tid/32.0; twc[tid] = (float)cos(a); tws[tid] = (float)sin(a); }
  __syncthreads();
  int aq = tid >> 5, c = tid & 31;
  uint32_t w0 = reinterpret_cast<uint32_t*>(tl)[c];
  float t0r = bf2f(w0);
  float U0=0,U1=0,U2=0,U3=0,V0=0,V1=0,V2=0,V3=0;
  int p = aq;
  #pragma unroll
  for (int m = 1; m < 16; ++m){
    uint32_t wv = reinterpret_cast<uint32_t*>(tl)[m*32 + c];
    float tr = bf2f(wv), ti = bf2f(wv >> 16);
    float C = twc[p], S = tws[p];
    float u = tr*C - ti*S;
    float v = tr*S + ti*C;
    int j = m & 3;
    if      (j == 0){ U0 += u; V0 += v; }
    else if (j == 1){ U1 += u; V1 += v; }
    else if (j == 2){ U2 += u; V2 += v; }
    else            { U3 += u; V3 += v; }
    p = (p + aq) & 31;
  }
  float bia = bias[(bok >> 5) & 127];
  float* op = out + (size_t)bok*1024 + c;
  op[aq*32]      = t0r + 2.f*(U0+U1+U2+U3) + bia;
  op[(aq+8)*32]  = t0r + 2.f*(U0-V1-U2+V3) + bia;
  op[(aq+16)*32] = t0r + 2.f*(U0-U1+U2-U3) + bia;
  op[(aq+24)*32] = t0r + 2.f*(U0+V1-U2-V3) + bia;
}

extern "C" void kernel_launch(void* const* d_in, const int* in_sizes, int n_in,
                              void* d_out, int out_size, void* d_ws, size_t ws_size,
                              hipStream_t stream) {
  const float* x    = (const float*)d_in[0];   // [8,64,64,64]
  const float* kern = (const float*)d_in[1];   // [64,128,32]
  const float* bias = (const float*)d_in[2];   // [128]
  float* out = (float*)d_out;                  // [8,128,32,32,32]
  float* ws  = (float*)d_ws;

  k_wana<<<dim3(124),  dim3(256), 0, stream>>>(ws);
  k_fk  <<<dim3(62),   dim3(256), 0, stream>>>(ws);
  k_dsyn<<<dim3(512),  dim3(256), 0, stream>>>(ws);
  k_xhat<<<dim3(512),  dim3(256), 0, stream>>>(x, ws);
  k_khc <<<dim3(2048), dim3(256), 0, stream>>>(kern, ws);
  k_z   <<<dim3(1024), dim3(256), 0, stream>>>(ws);
  k_fmn <<<dim3(1024), dim3(256), 0, stream>>>(ws);
  k_t   <<<dim3(16384),dim3(256), 0, stream>>>(ws);
  k_out <<<dim3(32768),dim3(256), 0, stream>>>(bias, out, ws);
}

// Round 3
// 531.372 us; speedup vs baseline: 2.4772x; 1.2046x over previous
//
#include <hip/hip_runtime.h>
#include <stdint.h>
#include <math.h>

// S2Convolution: BATCH=8, FIN=64, FOUT=128, B_IN=32, B_OUT=16, NL=16, MDIM=31,
// grid 4x8=32, out [8,128,32,32,32] fp32.
//
// v3: k_z single-barrier flattened 2x2-microtile form (bf16 LDS operands);
// khc computed for n'>=0 only (conj-parity symmetry applied when staging);
// fmn+t fused (fmn stays fp32 in LDS, never hits global); k_out 4 boks/block.

#define PI_D 3.14159265358979323846
#define SCALING_F 0.002762135864009951f   // 1/sqrt(32*64*16^4/32^2)

// ws offsets in 4-byte words.
#define OFF_WANA 0            // 64*16*31   = 31744
#define OFF_FKR  31744        // 32*16*31   = 15872
#define OFF_FKI  47616        // 15872
#define OFF_DP2  63488        // 32*2856    = 91392
#define OFF_XHAT 154880       // 16*31*8*64*2 = 507904
#define OFF_KHC  662784       // 136*128*128  = 2228224  ([tri-row n'>=0][o][i cpx])
#define OFF_Z    2891008      // 1024*2856*2  = 5849088
#define OFF_T    8740096      // 32768*16*32  = 16777216 (bf16-pair words)
// total = 25517312 words = 102 MB

// packed (l, m'>=0, n) offsets: c2_offs[l] = sum_{j<l} (j+1)(2j+1) = l(l+1)(4l-1)/6
__device__ __constant__ int c2_offs[17] =
  {0,1,7,22,50,95,161,252,372,525,715,946,1222,1547,1925,2360,2856};
// 2x2-microtile task offsets: t2_offs[l] = sum_{j<l} ceil((j+1)/2)*(j+1)
__device__ __constant__ int t2o_c[17] =
  {0,1,3,9,17,32,50,78,110,155,205,271,343,434,532,652,780};

__device__ inline double ipow_d(double x, int e){
  double r = 1.0;
  while (e > 0){ if (e & 1) r *= x; x *= x; e >>= 1; }
  return r;
}

// Wigner small-d d^l_{m1,m2}(beta), fp64, matches reference _wigner_d
__device__ double wig_d(int l, int m1, int m2, double beta, const double* LF){
  double c = cos(0.5*beta), s = sin(0.5*beta);
  double sum = 0.0;
  for (int k = 0; k <= 2*l; ++k){
    int a1 = l + m2 - k, a3 = m1 - m2 + k, a4 = l - m1 - k;
    if (a1 < 0 || a3 < 0 || a4 < 0) continue;
    double logc = 0.5*(LF[l+m1]+LF[l-m1]+LF[l+m2]+LF[l-m2]) - LF[a1] - LF[k] - LF[a3] - LF[a4];
    double t = exp(logc) * ipow_d(c, a1 + a4) * ipow_d(s, a3 + k);
    sum += (a3 & 1) ? -t : t;  // (-1)^(m1-m2+k)
  }
  return sum;
}

__device__ inline uint32_t f2bf(float f){
  uint32_t u = __float_as_uint(f);
  return (u + 0x7fffu + ((u >> 16) & 1u)) >> 16;   // RNE
}
__device__ inline float bf2f(uint32_t h){ return __uint_as_float((h & 0xffffu) << 16); }
__device__ inline uint32_t pack2(float a, float b){ return f2bf(a) | (f2bf(b) << 16); }

#define LF_INIT \
  __shared__ double LF[40]; \
  if (threadIdx.x == 0){ LF[0] = 0.0; double acc_ = 0.0; for (int n_ = 1; n_ < 40; ++n_){ acc_ += log((double)n_); LF[n_] = acc_; } } \
  __syncthreads();

// Merged constant tables: blocks [0,124) wana, [124,186) fk, [186,698) dsyn.
__global__ void k_consts(float* __restrict__ ws){
  LF_INIT
  int bid = blockIdx.x, tid = threadIdx.x;
  if (bid < 124){
    int id = bid*256 + tid;
    if (id >= 31744) return;
    int m = id % 31, l = (id / 31) & 15, j = id / 496;
    int mp = m - 15, amp = mp < 0 ? -mp : mp;
    float val = 0.f;
    if (amp <= l){
      double beta = PI_D*(2*j + 0.5)/128.0;
      double wsum = 0.0;
      for (int kk = 0; kk < 32; ++kk) wsum += sin(beta*(2*kk+1))/(double)(2*kk+1);
      double w = (2.0*PI_D/64.0)*(2.0/32.0)*sin(beta)*wsum;
      val = (float)(w * wig_d(l, mp, 0, beta, LF));
    }
    ws[OFF_WANA + id] = val;
  } else if (bid < 186){
    int id = (bid - 124)*256 + tid;
    if (id >= 15872) return;
    int n = id % 31, l = (id / 31) & 15, g = id / 496;
    int np = n - 15, anp = np < 0 ? -np : np;
    float vr = 0.f, vi = 0.f;
    if (anp <= l){
      double beta = PI_D*((double)((g >> 3) + 1))/32.0;
      double alpha = (PI_D/4.0)*(double)(g & 7);
      double d = wig_d(l, np, 0, beta, LF);
      vr = (float)(d*cos(np*alpha));
      vi = (float)(d*sin(np*alpha));
    }
    ws[OFF_FKR + id] = vr;
    ws[OFF_FKI + id] = vi;
  } else {
    int bb = bid - 186;
    int k = bb >> 4, l = bb & 15;
    int n21 = 2*l + 1, items = (l+1)*n21;
    double beta = PI_D*(2*k + 0.5)/64.0;
    float fl = (float)(2*l + 1);
    for (int item = tid; item < items; item += 256){
      int im = item / n21, in = item - (item/n21)*n21;
      ws[OFF_DP2 + k*2856 + c2_offs[l] + item] = fl * (float)wig_d(l, im, in - l, beta, LF);
    }
  }
}

// xhat[l][m=15+m'][b][i] (cpx fp32), only m'>=0 rows
__global__ void k_xhat(const float* __restrict__ x, float* __restrict__ ws){
  __shared__ float xl[4096];
  __shared__ float c64[64], s64[64];
  __shared__ float xmr[1024], xmi[1024];
  int tid = threadIdx.x;
  int b = blockIdx.x >> 6, i = blockIdx.x & 63;
  const float* xp = x + (b*64 + i)*4096;
  for (int idx = tid; idx < 4096; idx += 256) xl[idx] = xp[idx];
  if (tid < 64){ double a = 2.0*PI_D*tid/64.0; c64[tid] = (float)cos(a); s64[tid] = (float)sin(a); }
  __syncthreads();
  for (int item = tid; item < 1024; item += 256){
    int j = item >> 4, mi = item & 15;
    float re = 0.f, im = 0.f;
    const float* xr = xl + j*64;
    for (int a = 0; a < 64; ++a){
      int p = (mi*a) & 63;
      re += xr[a]*c64[p];
      im -= xr[a]*s64[p];
    }
    xmr[item] = re; xmi[item] = im;
  }
  __syncthreads();
  {
    int l = tid >> 4, mi = tid & 15;
    if (mi <= l){
      float rr = 0.f, ri = 0.f;
      for (int j = 0; j < 64; ++j){
        float w = ws[OFF_WANA + j*496 + l*31 + 15 + mi];
        rr += w * xmr[j*16 + mi];
        ri += w * xmi[j*16 + mi];
      }
      int dst = OFF_XHAT + ((l*31 + 15 + mi)*8 + b)*128 + i*2;
      ws[dst] = rr; ws[dst+1] = ri;
    }
  }
}

// khc[tri(l)+np][o][i] = SCALING * sum_g kernel[i,o,g] * conj(FK[g,l,15+np]), np in [0,l]
__global__ void k_khc(const float* __restrict__ kern, float* __restrict__ ws){
  __shared__ float kl2[32*66];       // [g][i], pad 66 (8B-aligned float2 reads)
  __shared__ float fr[992], fi[992];
  int tid = threadIdx.x;
  int o = blockIdx.x >> 4, l = blockIdx.x & 15;
  for (int idx = tid; idx < 2048; idx += 256){
    int i = idx >> 5, g = idx & 31;
    kl2[g*66 + i] = kern[(i*128 + o)*32 + g];
  }
  for (int idx = tid; idx < 992; idx += 256){
    int g = idx / 31, n = idx - (idx/31)*31;
    fr[idx] = ws[OFF_FKR + g*496 + l*31 + n];
    fi[idx] = ws[OFF_FKI + g*496 + l*31 + n];
  }
  __syncthreads();
  int c1 = (l*(l+1)) >> 1;
  int ntask = (l+1)*32;
  for (int t = tid; t < ntask; t += 256){
    int np = t >> 5, ip = t & 31, i0 = 2*ip;
    float ar0=0.f, ai0=0.f, ar1=0.f, ai1=0.f;
    for (int g = 0; g < 32; ++g){
      float2 kv = *reinterpret_cast<const float2*>(kl2 + g*66 + i0);
      float fv = fr[g*31 + 15 + np], gv = fi[g*31 + 15 + np];
      ar0 += kv.x*fv; ai0 -= kv.x*gv;
      ar1 += kv.y*fv; ai1 -= kv.y*gv;
    }
    float4 v = make_float4(SCALING_F*ar0, SCALING_F*ai0, SCALING_F*ar1, SCALING_F*ai1);
    *reinterpret_cast<float4*>(ws + OFF_KHC + (size_t)((c1 + np)*128 + o)*128 + 2*i0) = v;
  }
}

// z[bo][c2-packed(l, m'>=0, n)] = sum_i xhat*conj(kh). Flattened 2x2 microtiles,
// bf16 LDS operands, two l-phases (l=0..11, l=12..15), one barrier per phase.
__global__ void k_z(float* __restrict__ ws){
  __shared__ uint32_t xb_[5070];   // max 78 rows * 65
  __shared__ uint32_t kb_[9360];   // max 144 rows * 65
  __shared__ int t2s[17];
  int tid = threadIdx.x, bo = blockIdx.x, b = bo >> 7, o = bo & 127;
  if (tid < 17) t2s[tid] = t2o_c[tid];
  for (int ph = 0; ph < 2; ++ph){
    int xrows = ph ? 58 : 78;
    int krows = ph ? 112 : 144;
    int trilo = ph ? 78 : 0;     // tri(12)
    int sqlo  = ph ? 144 : 0;    // 12^2
    if (ph) __syncthreads();
    for (int idx = tid; idx < xrows*64; idx += 256){
      int row = idx >> 6, i = idx & 63;
      int grow = row + trilo;
      float s = sqrtf(8.f*grow + 1.5f);
      int l = (int)((s - 1.f)*0.5f);
      int mi = grow - ((l*(l+1)) >> 1);
      const float* src = ws + OFF_XHAT + ((l*31 + 15 + mi)*8 + b)*128 + 2*i;
      xb_[row*65 + i] = pack2(src[0], src[1]);
    }
    for (int idx = tid; idx < krows*64; idx += 256){
      int row = idx >> 6, i = idx & 63;
      int grow = row + sqlo;
      int l = (int)sqrtf((float)grow + 0.5f);
      int nprime = grow - l*l - l;
      int np = nprime < 0 ? -nprime : nprime;
      const float* src = ws + OFF_KHC + (size_t)((((l*(l+1))>>1) + np)*128 + o)*128 + 2*i;
      float re = src[0], im = src[1];
      if (nprime < 0){ if (np & 1) re = -re; else im = -im; }  // (-1)^n conj
      kb_[row*65 + i] = pack2(re, im);
    }
    __syncthreads();
    int tlo = t2s[ph ? 12 : 0], thi = t2s[ph ? 16 : 12];
    for (int task = tlo + tid; task < thi; task += 256){
      int l = (task>=1)+(task>=3)+(task>=9)+(task>=17)+(task>=32)+(task>=50)+(task>=78)
            +(task>=110)+(task>=155)+(task>=205)+(task>=271)+(task>=343)+(task>=434)
            +(task>=532)+(task>=652);
      int rem = task - t2s[l];
      int ncols = l + 1;
      int tm = rem / ncols, tn = rem - tm*ncols;
      int l2 = 2*l;
      int im0 = 2*tm; int im1 = im0 + 1 > l  ? l  : im0 + 1;
      int in0 = 2*tn; int in1 = in0 + 1 > l2 ? l2 : in0 + 1;
      const uint32_t* x0 = xb_ + (((l*(l+1))>>1) - trilo + im0)*65;
      const uint32_t* x1 = xb_ + (((l*(l+1))>>1) - trilo + im1)*65;
      const uint32_t* k0 = kb_ + (l*l - sqlo + in0)*65;
      const uint32_t* k1 = kb_ + (l*l - sqlo + in1)*65;
      float z00r=0,z00i=0,z01r=0,z01i=0,z10r=0,z10i=0,z11r=0,z11i=0;
      for (int i = 0; i < 64; ++i){
        uint32_t xw0 = x0[i], xw1 = x1[i], kw0 = k0[i], kw1 = k1[i];
        float x0r = bf2f(xw0), x0i = bf2f(xw0 >> 16);
        float x1r = bf2f(xw1), x1i = bf2f(xw1 >> 16);
        float k0r = bf2f(kw0), k0i = bf2f(kw0 >> 16);
        float k1r = bf2f(kw1), k1i = bf2f(kw1 >> 16);
        z00r += x0r*k0r - x0i*k0i; z00i += x0r*k0i + x0i*k0r;
        z01r += x0r*k1r - x0i*k1i; z01i += x0r*k1i + x0i*k1r;
        z10r += x1r*k0r - x1i*k0i; z10i += x1r*k0i + x1i*k0r;
        z11r += x1r*k1r - x1i*k1i; z11i += x1r*k1i + x1i*k1r;
      }
      int n21 = l2 + 1;
      int c2 = (l*(l+1)*(4*l - 1))/6;
      float* zb = ws + OFF_Z + ((size_t)bo*2856 + c2)*2;
      *reinterpret_cast<float2*>(zb + (im0*n21 + in0)*2) = make_float2(z00r, z00i);
      *reinterpret_cast<float2*>(zb + (im0*n21 + in1)*2) = make_float2(z01r, z01i);
      *reinterpret_cast<float2*>(zb + (im1*n21 + in0)*2) = make_float2(z10r, z10i);
      *reinterpret_cast<float2*>(zb + (im1*n21 + in1)*2) = make_float2(z11r, z11i);
    }
  }
}

// Fused fmn + t: per (bo, k-group of 8). z staged once; fmn stays fp32 in LDS;
// 2 k's per pass; DFT over n with radix-4 class accumulation -> t (bf16 pairs).
__global__ void k_ft(float* __restrict__ ws){
  __shared__ float zl[5712];
  __shared__ float dk2[5712];
  __shared__ float fm2[1984];
  __shared__ float2 tw2[32];
  int tid = threadIdx.x;
  int bo = blockIdx.x >> 2, kg = (blockIdx.x & 3) << 3;
  if (tid < 32){ double a = 2.0*PI_D*tid/32.0; tw2[tid] = make_float2((float)cos(a), (float)sin(a)); }
  {
    const float4* zsrc = reinterpret_cast<const float4*>(ws + OFF_Z + (size_t)bo*5712);
    float4* zl4 = reinterpret_cast<float4*>(zl);
    for (int idx = tid; idx < 1428; idx += 256) zl4[idx] = zsrc[idx];
  }
  uint32_t* tbase = reinterpret_cast<uint32_t*>(ws) + OFF_T;
  for (int kp = 0; kp < 4; ++kp){
    if (kp) __syncthreads();
    {
      const float4* dsrc = reinterpret_cast<const float4*>(ws + OFF_DP2 + (size_t)(kg + 2*kp)*2856);
      float4* dk4 = reinterpret_cast<float4*>(dk2);
      for (int idx = tid; idx < 1428; idx += 256) dk4[idx] = dsrc[idx];
    }
    __syncthreads();
    for (int idx = tid; idx < 992; idx += 256){
      int ks = (idx >= 496) ? 1 : 0;
      int it = idx - 496*ks;
      int m = it / 31, n = it - m*31;
      int np = n - 15, an = np < 0 ? -np : np;
      int lmin = m > an ? m : an;
      float Fr = 0.f, Fi = 0.f;
      const float* dk = dk2 + ks*2856;
      for (int l = 15; l >= lmin; --l){
        int idx2 = c2_offs[l] + m*(2*l + 1) + (n - 15 + l);
        float d = dk[idx2];
        float2 zv = *reinterpret_cast<const float2*>(zl + 2*idx2);
        Fr += d*zv.x; Fi += d*zv.y;
      }
      fm2[ks*992 + 2*it]     = Fr;
      fm2[ks*992 + 2*it + 1] = Fi;
    }
    __syncthreads();
    {
      int ks = tid >> 7, r = tid & 127, m = r >> 3, cq = r & 7;
      const float2* fr2 = reinterpret_cast<const float2*>(fm2 + ks*992) + m*31;
      float U0=0,U1=0,U2=0,U3=0,V0=0,V1=0,V2=0,V3=0;
      int p = (17*cq) & 31;
      #pragma unroll
      for (int n = 0; n < 31; ++n){
        float2 F = fr2[n];
        float2 T = tw2[p];
        float u = F.x*T.x - F.y*T.y;
        float v = F.x*T.y + F.y*T.x;
        int j = (n + 1) & 3;
        if      (j == 0){ U0 += u; V0 += v; }
        else if (j == 1){ U1 += u; V1 += v; }
        else if (j == 2){ U2 += u; V2 += v; }
        else            { U3 += u; V3 += v; }
        p = (p + cq) & 31;
      }
      int bok = bo*32 + kg + 2*kp + ks;
      uint32_t* tp = tbase + (size_t)(bok*16 + m)*32 + cq;
      tp[0]  = pack2(U0+U1+U2+U3, V0+V1+V2+V3);
      tp[8]  = pack2(U0-V1-U2+V3, V0+U1-V2-U3);
      tp[16] = pack2(U0-U1+U2-U3, V0-V1+V2-V3);
      tp[24] = pack2(U0+V1-U2-V3, V0-U1-V2+U3);
    }
  }
}

// out[bok][a][c] = t0.re + sum_{m'=1..15} 2 Re(t[m',c] e^{i 2pi a m'/32}) + bias.
// 4 boks per block.
__global__ void k_out(const float* __restrict__ bias, float* __restrict__ out,
                      const float* __restrict__ ws){
  __shared__ uint32_t tl[2048];
  __shared__ float2 tw2[32];
  int tid = threadIdx.x;
  int b4 = blockIdx.x*4;
  const uint32_t* tg = reinterpret_cast<const uint32_t*>(ws) + OFF_T + (size_t)b4*512;
  for (int idx = tid; idx < 2048; idx += 256) tl[idx] = tg[idx];
  if (tid < 32){ double a = 2.0*PI_D*tid/32.0; tw2[tid] = make_float2((float)cos(a), (float)sin(a)); }
  __syncthreads();
  int aq = tid >> 5, c = tid & 31;
  for (int q = 0; q < 4; ++q){
    int bok = b4 + q;
    const uint32_t* tq = tl + q*512;
    float t0r = bf2f(tq[c]);
    float U0=0,U1=0,U2=0,U3=0,V0=0,V1=0,V2=0,V3=0;
    int p = aq;
    #pragma unroll
    for (int m = 1; m < 16; ++m){
      uint32_t wv = tq[m*32 + c];
      float tr = bf2f(wv), ti = bf2f(wv >> 16);
      float2 T = tw2[p];
      float u = tr*T.x - ti*T.y;
      float v = tr*T.y + ti*T.x;
      int j = m & 3;
      if      (j == 0){ U0 += u; V0 += v; }
      else if (j == 1){ U1 += u; V1 += v; }
      else if (j == 2){ U2 += u; V2 += v; }
      else            { U3 += u; V3 += v; }
      p = (p + aq) & 31;
    }
    float bia = bias[(bok >> 5) & 127];
    float* op = out + (size_t)bok*1024 + c;
    op[aq*32]      = t0r + 2.f*(U0+U1+U2+U3) + bia;
    op[(aq+8)*32]  = t0r + 2.f*(U0-V1-U2+V3) + bia;
    op[(aq+16)*32] = t0r + 2.f*(U0-U1+U2-U3) + bia;
    op[(aq+24)*32] = t0r + 2.f*(U0+V1-U2-V3) + bia;
  }
}

extern "C" void kernel_launch(void* const* d_in, const int* in_sizes, int n_in,
                              void* d_out, int out_size, void* d_ws, size_t ws_size,
                              hipStream_t stream) {
  const float* x    = (const float*)d_in[0];   // [8,64,64,64]
  const float* kern = (const float*)d_in[1];   // [64,128,32]
  const float* bias = (const float*)d_in[2];   // [128]
  float* out = (float*)d_out;                  // [8,128,32,32,32]
  float* ws  = (float*)d_ws;

  k_consts<<<dim3(698),  dim3(256), 0, stream>>>(ws);
  k_xhat  <<<dim3(512),  dim3(256), 0, stream>>>(x, ws);
  k_khc   <<<dim3(2048), dim3(256), 0, stream>>>(kern, ws);
  k_z     <<<dim3(1024), dim3(256), 0, stream>>>(ws);
  k_ft    <<<dim3(4096), dim3(256), 0, stream>>>(ws);
  k_out   <<<dim3(8192), dim3(256), 0, stream>>>(bias, out, ws);
}

// Round 4
// 514.296 us; speedup vs baseline: 2.5595x; 1.0332x over previous
//
#include <hip/hip_runtime.h>
#include <stdint.h>
#include <math.h>

// S2Convolution: BATCH=8, FIN=64, FOUT=128, B_IN=32, B_OUT=16, NL=16, MDIM=31,
// grid 4x8=32, out [8,128,32,32,32] fp32.
//
// v4: dense-l layouts. z2[bo][mn][l] bf16 pairs (zero-padded), D3[k][mn][l]
// fp32 dense (zero-padded, L2-resident). k_ft: fixed-16 vectorized dots,
// D3 read straight from global (no staging barriers), 3 blocks/CU.

#define PI_D 3.14159265358979323846
#define SCALING_F 0.002762135864009951f   // 1/sqrt(32*64*16^4/32^2)

// ws offsets in 4-byte words.
#define OFF_WANA 0            // 64*16*31   = 31744
#define OFF_FKR  31744        // 32*16*31   = 15872
#define OFF_FKI  47616        // 15872
#define OFF_D3   63488        // 32*496*16  = 253952  (dense fp32 [k][mn][l])
#define OFF_XHAT 317440       // 16*31*8*64*2 = 507904
#define OFF_KHC  825344       // 136*128*128  = 2228224 ([tri-row n'>=0][o][i cpx])
#define OFF_Z2   3053568      // 1024*496*16  = 8126464 (dense bf16-pair [bo][mn][l])
#define OFF_T    11180032     // 32768*16*32  = 16777216 (bf16-pair words)
// total = 27957248 words = 112 MB

// packed (l, m'>=0, n) offsets: c2_offs[l] = sum_{j<l} (j+1)(2j+1)
__device__ __constant__ int c2_offs[17] =
  {0,1,7,22,50,95,161,252,372,525,715,946,1222,1547,1925,2360,2856};
// 2x2-microtile task offsets
__device__ __constant__ int t2o_c[17] =
  {0,1,3,9,17,32,50,78,110,155,205,271,343,434,532,652,780};

__device__ inline double ipow_d(double x, int e){
  double r = 1.0;
  while (e > 0){ if (e & 1) r *= x; x *= x; e >>= 1; }
  return r;
}

// Wigner small-d d^l_{m1,m2}(beta), fp64, matches reference _wigner_d
__device__ double wig_d(int l, int m1, int m2, double beta, const double* LF){
  double c = cos(0.5*beta), s = sin(0.5*beta);
  double sum = 0.0;
  for (int k = 0; k <= 2*l; ++k){
    int a1 = l + m2 - k, a3 = m1 - m2 + k, a4 = l - m1 - k;
    if (a1 < 0 || a3 < 0 || a4 < 0) continue;
    double logc = 0.5*(LF[l+m1]+LF[l-m1]+LF[l+m2]+LF[l-m2]) - LF[a1] - LF[k] - LF[a3] - LF[a4];
    double t = exp(logc) * ipow_d(c, a1 + a4) * ipow_d(s, a3 + k);
    sum += (a3 & 1) ? -t : t;  // (-1)^(m1-m2+k)
  }
  return sum;
}

__device__ inline uint32_t f2bf(float f){
  uint32_t u = __float_as_uint(f);
  return (u + 0x7fffu + ((u >> 16) & 1u)) >> 16;   // RNE
}
__device__ inline float bf2f(uint32_t h){ return __uint_as_float((h & 0xffffu) << 16); }
__device__ inline float bf2f_lo(uint32_t h){ return __uint_as_float(h << 16); }
__device__ inline float bf2f_hi(uint32_t h){ return __uint_as_float(h & 0xffff0000u); }
__device__ inline uint32_t pack2(float a, float b){ return f2bf(a) | (f2bf(b) << 16); }

#define LF_INIT \
  __shared__ double LF[40]; \
  if (threadIdx.x == 0){ LF[0] = 0.0; double acc_ = 0.0; for (int n_ = 1; n_ < 40; ++n_){ acc_ += log((double)n_); LF[n_] = acc_; } } \
  __syncthreads();

// zero D3 (so dense l-dots see 0 in invalid slots). 248 blocks x 256 x float4.
__global__ void k_zero(float* __restrict__ ws){
  int id = blockIdx.x*256 + threadIdx.x;
  *reinterpret_cast<float4*>(ws + OFF_D3 + (size_t)id*4) = make_float4(0.f,0.f,0.f,0.f);
}

// Merged constant tables: blocks [0,124) wana, [124,186) fk, [186,698) dsyn->D3.
__global__ void k_consts(float* __restrict__ ws){
  LF_INIT
  int bid = blockIdx.x, tid = threadIdx.x;
  if (bid < 124){
    int id = bid*256 + tid;
    if (id >= 31744) return;
    int m = id % 31, l = (id / 31) & 15, j = id / 496;
    int mp = m - 15, amp = mp < 0 ? -mp : mp;
    float val = 0.f;
    if (amp <= l){
      double beta = PI_D*(2*j + 0.5)/128.0;
      double wsum = 0.0;
      for (int kk = 0; kk < 32; ++kk) wsum += sin(beta*(2*kk+1))/(double)(2*kk+1);
      double w = (2.0*PI_D/64.0)*(2.0/32.0)*sin(beta)*wsum;
      val = (float)(w * wig_d(l, mp, 0, beta, LF));
    }
    ws[OFF_WANA + id] = val;
  } else if (bid < 186){
    int id = (bid - 124)*256 + tid;
    if (id >= 15872) return;
    int n = id % 31, l = (id / 31) & 15, g = id / 496;
    int np = n - 15, anp = np < 0 ? -np : np;
    float vr = 0.f, vi = 0.f;
    if (anp <= l){
      double beta = PI_D*((double)((g >> 3) + 1))/32.0;
      double alpha = (PI_D/4.0)*(double)(g & 7);
      double d = wig_d(l, np, 0, beta, LF);
      vr = (float)(d*cos(np*alpha));
      vi = (float)(d*sin(np*alpha));
    }
    ws[OFF_FKR + id] = vr;
    ws[OFF_FKI + id] = vi;
  } else {
    int bb = bid - 186;
    int k = bb >> 4, l = bb & 15;
    int n21 = 2*l + 1, items = (l+1)*n21;
    double beta = PI_D*(2*k + 0.5)/64.0;
    float fl = (float)(2*l + 1);
    for (int item = tid; item < items; item += 256){
      int im = item / n21, in = item - (item/n21)*n21;
      // mn = im*31 + (n'+15), n' = in - l
      ws[OFF_D3 + (size_t)(k*496 + im*31 + in - l + 15)*16 + l]
        = fl * (float)wig_d(l, im, in - l, beta, LF);
    }
  }
}

// xhat[l][m=15+m'][b][i] (cpx fp32), only m'>=0 rows
__global__ void k_xhat(const float* __restrict__ x, float* __restrict__ ws){
  __shared__ float xl[4096];
  __shared__ float c64[64], s64[64];
  __shared__ float xmr[1024], xmi[1024];
  int tid = threadIdx.x;
  int b = blockIdx.x >> 6, i = blockIdx.x & 63;
  const float* xp = x + (b*64 + i)*4096;
  for (int idx = tid; idx < 4096; idx += 256) xl[idx] = xp[idx];
  if (tid < 64){ double a = 2.0*PI_D*tid/64.0; c64[tid] = (float)cos(a); s64[tid] = (float)sin(a); }
  __syncthreads();
  for (int item = tid; item < 1024; item += 256){
    int j = item >> 4, mi = item & 15;
    float re = 0.f, im = 0.f;
    const float* xr = xl + j*64;
    for (int a = 0; a < 64; ++a){
      int p = (mi*a) & 63;
      re += xr[a]*c64[p];
      im -= xr[a]*s64[p];
    }
    xmr[item] = re; xmi[item] = im;
  }
  __syncthreads();
  {
    int l = tid >> 4, mi = tid & 15;
    if (mi <= l){
      float rr = 0.f, ri = 0.f;
      for (int j = 0; j < 64; ++j){
        float w = ws[OFF_WANA + j*496 + l*31 + 15 + mi];
        rr += w * xmr[j*16 + mi];
        ri += w * xmi[j*16 + mi];
      }
      int dst = OFF_XHAT + ((l*31 + 15 + mi)*8 + b)*128 + i*2;
      ws[dst] = rr; ws[dst+1] = ri;
    }
  }
}

// khc[tri(l)+np][o][i] = SCALING * sum_g kernel[i,o,g] * conj(FK[g,l,15+np]), np in [0,l]
__global__ void k_khc(const float* __restrict__ kern, float* __restrict__ ws){
  __shared__ float kl2[32*66];
  __shared__ float fr[992], fi[992];
  int tid = threadIdx.x;
  int o = blockIdx.x >> 4, l = blockIdx.x & 15;
  for (int idx = tid; idx < 2048; idx += 256){
    int i = idx >> 5, g = idx & 31;
    kl2[g*66 + i] = kern[(i*128 + o)*32 + g];
  }
  for (int idx = tid; idx < 992; idx += 256){
    int g = idx / 31, n = idx - (idx/31)*31;
    fr[idx] = ws[OFF_FKR + g*496 + l*31 + n];
    fi[idx] = ws[OFF_FKI + g*496 + l*31 + n];
  }
  __syncthreads();
  int c1 = (l*(l+1)) >> 1;
  int ntask = (l+1)*32;
  for (int t = tid; t < ntask; t += 256){
    int np = t >> 5, ip = t & 31, i0 = 2*ip;
    float ar0=0.f, ai0=0.f, ar1=0.f, ai1=0.f;
    for (int g = 0; g < 32; ++g){
      float2 kv = *reinterpret_cast<const float2*>(kl2 + g*66 + i0);
      float fv = fr[g*31 + 15 + np], gv = fi[g*31 + 15 + np];
      ar0 += kv.x*fv; ai0 -= kv.x*gv;
      ar1 += kv.y*fv; ai1 -= kv.y*gv;
    }
    float4 v = make_float4(SCALING_F*ar0, SCALING_F*ai0, SCALING_F*ar1, SCALING_F*ai1);
    *reinterpret_cast<float4*>(ws + OFF_KHC + (size_t)((c1 + np)*128 + o)*128 + 2*i0) = v;
  }
}

// z2[bo][mn][l] (bf16 pair, zero-padded l<lmin) = sum_i xhat*conj(kh).
// Flattened 2x2 microtiles, bf16 LDS operands, two l-phases.
__global__ void k_z(float* __restrict__ ws){
  __shared__ uint32_t xb_[5070];   // max 78 rows * 65
  __shared__ uint32_t kb_[9360];   // max 144 rows * 65
  __shared__ int t2s[17];
  int tid = threadIdx.x, bo = blockIdx.x, b = bo >> 7, o = bo & 127;
  if (tid < 17) t2s[tid] = t2o_c[tid];
  uint32_t* z2g = reinterpret_cast<uint32_t*>(ws) + OFF_Z2 + (size_t)bo*7936;
  // zero-fill invalid (mn,l) slots (valid ones written by tasks below; disjoint)
  for (int idx = tid; idx < 7936; idx += 256){
    int mn = idx >> 4, l = idx & 15;
    int m = mn / 31, nd = mn - m*31, np = nd - 15, an = np < 0 ? -np : np;
    int lmin = m > an ? m : an;
    if (l < lmin) z2g[idx] = 0u;
  }
  for (int ph = 0; ph < 2; ++ph){
    int xrows = ph ? 58 : 78;
    int krows = ph ? 112 : 144;
    int trilo = ph ? 78 : 0;     // tri(12)
    int sqlo  = ph ? 144 : 0;    // 12^2
    if (ph) __syncthreads();
    for (int idx = tid; idx < xrows*64; idx += 256){
      int row = idx >> 6, i = idx & 63;
      int grow = row + trilo;
      float s = sqrtf(8.f*grow + 1.5f);
      int l = (int)((s - 1.f)*0.5f);
      int mi = grow - ((l*(l+1)) >> 1);
      float2 v = *reinterpret_cast<const float2*>(ws + OFF_XHAT + ((l*31 + 15 + mi)*8 + b)*128 + 2*i);
      xb_[row*65 + i] = pack2(v.x, v.y);
    }
    for (int idx = tid; idx < krows*64; idx += 256){
      int row = idx >> 6, i = idx & 63;
      int grow = row + sqlo;
      int l = (int)sqrtf((float)grow + 0.5f);
      int nprime = grow - l*l - l;
      int np = nprime < 0 ? -nprime : nprime;
      float2 v = *reinterpret_cast<const float2*>(ws + OFF_KHC + (size_t)((((l*(l+1))>>1) + np)*128 + o)*128 + 2*i);
      float re = v.x, im = v.y;
      if (nprime < 0){ if (np & 1) re = -re; else im = -im; }  // (-1)^n conj
      kb_[row*65 + i] = pack2(re, im);
    }
    __syncthreads();
    int tlo = t2s[ph ? 12 : 0], thi = t2s[ph ? 16 : 12];
    for (int task = tlo + tid; task < thi; task += 256){
      int l = (task>=1)+(task>=3)+(task>=9)+(task>=17)+(task>=32)+(task>=50)+(task>=78)
            +(task>=110)+(task>=155)+(task>=205)+(task>=271)+(task>=343)+(task>=434)
            +(task>=532)+(task>=652);
      int rem = task - t2s[l];
      int ncols = l + 1;
      int tm = rem / ncols, tn = rem - tm*ncols;
      int l2 = 2*l;
      int im0 = 2*tm; int im1 = im0 + 1 > l  ? l  : im0 + 1;
      int in0 = 2*tn; int in1 = in0 + 1 > l2 ? l2 : in0 + 1;
      const uint32_t* x0 = xb_ + (((l*(l+1))>>1) - trilo + im0)*65;
      const uint32_t* x1 = xb_ + (((l*(l+1))>>1) - trilo + im1)*65;
      const uint32_t* k0 = kb_ + (l*l - sqlo + in0)*65;
      const uint32_t* k1 = kb_ + (l*l - sqlo + in1)*65;
      float z00r=0,z00i=0,z01r=0,z01i=0,z10r=0,z10i=0,z11r=0,z11i=0;
      for (int i = 0; i < 64; ++i){
        uint32_t xw0 = x0[i], xw1 = x1[i], kw0 = k0[i], kw1 = k1[i];
        float x0r = bf2f_lo(xw0), x0i = bf2f_hi(xw0);
        float x1r = bf2f_lo(xw1), x1i = bf2f_hi(xw1);
        float k0r = bf2f_lo(kw0), k0i = bf2f_hi(kw0);
        float k1r = bf2f_lo(kw1), k1i = bf2f_hi(kw1);
        z00r += x0r*k0r - x0i*k0i; z00i += x0r*k0i + x0i*k0r;
        z01r += x0r*k1r - x0i*k1i; z01i += x0r*k1i + x0i*k1r;
        z10r += x1r*k0r - x1i*k0i; z10i += x1r*k0i + x1i*k0r;
        z11r += x1r*k1r - x1i*k1i; z11i += x1r*k1i + x1i*k1r;
      }
      // dense write: word (im*31 + in - l + 15)*16 + l
      z2g[(im0*31 + in0 - l + 15)*16 + l] = pack2(z00r, z00i);
      z2g[(im0*31 + in1 - l + 15)*16 + l] = pack2(z01r, z01i);
      z2g[(im1*31 + in0 - l + 15)*16 + l] = pack2(z10r, z10i);
      z2g[(im1*31 + in1 - l + 15)*16 + l] = pack2(z11r, z11i);
    }
  }
}

// Fused fmn + t, v4: one block per bo. z2 staged once (bf16 pairs, 31.7KB).
// fmn = fixed-16 dot: 4x global float4 (D3, L2) + 4x ds_read_b128 (z2).
// fm fp32 in LDS (row pad 498), then radix-4 DFT over n -> t (bf16 pairs).
__global__ void k_ft(float* __restrict__ ws){
  __shared__ uint32_t z2l[7936];   // [mn][l] bf16 pairs
  __shared__ float fm[3984];       // [kk<4][498 float2]
  __shared__ float2 tw2[32];
  int tid = threadIdx.x, bo = blockIdx.x;
  if (tid < 32){ double a = 2.0*PI_D*tid/32.0; tw2[tid] = make_float2((float)cos(a), (float)sin(a)); }
  {
    const uint4* zsrc = reinterpret_cast<const uint4*>(reinterpret_cast<const uint32_t*>(ws) + OFF_Z2 + (size_t)bo*7936);
    uint4* zdst = reinterpret_cast<uint4*>(z2l);
    for (int idx = tid; idx < 1984; idx += 256) zdst[idx] = zsrc[idx];
  }
  __syncthreads();
  const uint4* zl4 = reinterpret_cast<const uint4*>(z2l);
  uint32_t* tbase = reinterpret_cast<uint32_t*>(ws) + OFF_T;
  for (int kg = 0; kg < 8; ++kg){
    if (kg) __syncthreads();
    // phase A: fmn for k = kg*4 .. kg*4+3
    #pragma unroll
    for (int it8 = 0; it8 < 8; ++it8){
      int item = it8*256 + tid;
      if (item < 1984){
        int kk = item & 3, mn = item >> 2;
        int k = kg*4 + kk;
        const float4* Dp = reinterpret_cast<const float4*>(ws + OFF_D3 + (size_t)(k*496 + mn)*16);
        float Fr = 0.f, Fi = 0.f;
        #pragma unroll
        for (int c = 0; c < 4; ++c){
          float4 d = Dp[c];
          uint4 zv = zl4[mn*4 + c];
          Fr += d.x*bf2f_lo(zv.x) + d.y*bf2f_lo(zv.y) + d.z*bf2f_lo(zv.z) + d.w*bf2f_lo(zv.w);
          Fi += d.x*bf2f_hi(zv.x) + d.y*bf2f_hi(zv.y) + d.z*bf2f_hi(zv.z) + d.w*bf2f_hi(zv.w);
        }
        *reinterpret_cast<float2*>(fm + (kk*498 + mn)*2) = make_float2(Fr, Fi);
      }
    }
    __syncthreads();
    // phase B: t-DFT over n (radix-4 classes), 512 slots
    #pragma unroll
    for (int sp = 0; sp < 2; ++sp){
      int s = sp*256 + tid;
      int kk = s >> 7, r = s & 127, m = r >> 3, cq = r & 7;
      const float2* fr2 = reinterpret_cast<const float2*>(fm) + kk*498 + m*31;
      float U0=0,U1=0,U2=0,U3=0,V0=0,V1=0,V2=0,V3=0;
      int p = (17*cq) & 31;
      #pragma unroll
      for (int n = 0; n < 31; ++n){
        float2 F = fr2[n];
        float2 T = tw2[p];
        float u = F.x*T.x - F.y*T.y;
        float v = F.x*T.y + F.y*T.x;
        int j = (n + 1) & 3;
        if      (j == 0){ U0 += u; V0 += v; }
        else if (j == 1){ U1 += u; V1 += v; }
        else if (j == 2){ U2 += u; V2 += v; }
        else            { U3 += u; V3 += v; }
        p = (p + cq) & 31;
      }
      int bok = bo*32 + kg*4 + kk;
      uint32_t* tp = tbase + (size_t)(bok*16 + m)*32 + cq;
      tp[0]  = pack2(U0+U1+U2+U3, V0+V1+V2+V3);
      tp[8]  = pack2(U0-V1-U2+V3, V0+U1-V2-U3);
      tp[16] = pack2(U0-U1+U2-U3, V0-V1+V2-V3);
      tp[24] = pack2(U0+V1-U2-V3, V0-U1-V2+U3);
    }
  }
}

// out[bok][a][c] = t0.re + sum_{m'=1..15} 2 Re(t[m',c] e^{i 2pi a m'/32}) + bias.
// 4 boks per block.
__global__ void k_out(const float* __restrict__ bias, float* __restrict__ out,
                      const float* __restrict__ ws){
  __shared__ uint32_t tl[2048];
  __shared__ float2 tw2[32];
  int tid = threadIdx.x;
  int b4 = blockIdx.x*4;
  const uint32_t* tg = reinterpret_cast<const uint32_t*>(ws) + OFF_T + (size_t)b4*512;
  for (int idx = tid; idx < 2048; idx += 256) tl[idx] = tg[idx];
  if (tid < 32){ double a = 2.0*PI_D*tid/32.0; tw2[tid] = make_float2((float)cos(a), (float)sin(a)); }
  __syncthreads();
  int aq = tid >> 5, c = tid & 31;
  for (int q = 0; q < 4; ++q){
    int bok = b4 + q;
    const uint32_t* tq = tl + q*512;
    float t0r = bf2f(tq[c]);
    float U0=0,U1=0,U2=0,U3=0,V0=0,V1=0,V2=0,V3=0;
    int p = aq;
    #pragma unroll
    for (int m = 1; m < 16; ++m){
      uint32_t wv = tq[m*32 + c];
      float tr = bf2f_lo(wv), ti = bf2f_hi(wv);
      float2 T = tw2[p];
      float u = tr*T.x - ti*T.y;
      float v = tr*T.y + ti*T.x;
      int j = m & 3;
      if      (j == 0){ U0 += u; V0 += v; }
      else if (j == 1){ U1 += u; V1 += v; }
      else if (j == 2){ U2 += u; V2 += v; }
      else            { U3 += u; V3 += v; }
      p = (p + aq) & 31;
    }
    float bia = bias[(bok >> 5) & 127];
    float* op = out + (size_t)bok*1024 + c;
    op[aq*32]      = t0r + 2.f*(U0+U1+U2+U3) + bia;
    op[(aq+8)*32]  = t0r + 2.f*(U0-V1-U2+V3) + bia;
    op[(aq+16)*32] = t0r + 2.f*(U0-U1+U2-U3) + bia;
    op[(aq+24)*32] = t0r + 2.f*(U0+V1-U2-V3) + bia;
  }
}

extern "C" void kernel_launch(void* const* d_in, const int* in_sizes, int n_in,
                              void* d_out, int out_size, void* d_ws, size_t ws_size,
                              hipStream_t stream) {
  const float* x    = (const float*)d_in[0];   // [8,64,64,64]
  const float* kern = (const float*)d_in[1];   // [64,128,32]
  const float* bias = (const float*)d_in[2];   // [128]
  float* out = (float*)d_out;                  // [8,128,32,32,32]
  float* ws  = (float*)d_ws;

  k_zero  <<<dim3(248),  dim3(256), 0, stream>>>(ws);
  k_consts<<<dim3(698),  dim3(256), 0, stream>>>(ws);
  k_xhat  <<<dim3(512),  dim3(256), 0, stream>>>(x, ws);
  k_khc   <<<dim3(2048), dim3(256), 0, stream>>>(kern, ws);
  k_z     <<<dim3(1024), dim3(256), 0, stream>>>(ws);
  k_ft    <<<dim3(1024), dim3(256), 0, stream>>>(ws);
  k_out   <<<dim3(8192), dim3(256), 0, stream>>>(bias, out, ws);
}